// Round 3
// baseline (71.714 us; speedup 1.0000x reference)
//
#include <hip/hip_runtime.h>
#include <math.h>

// (B,T,C)=(16,2048,1024), H=16, K=31, R=64, causal pad P=30.
// out[b,t,c] = sum_{j=0..30} w_rev[h(c),j] * x[b,t-j,c],  w_rev[j] = softmax(w)[30-j]
#define TPB 256
#define KW  31
constexpr int B_ = 16, T_ = 2048, C_ = 1024, H_ = 16;

__global__ void softmax_rev_kernel(const float* __restrict__ w, float* __restrict__ wr) {
    int h = threadIdx.x;
    if (h < H_) {
        float v[KW];
        float m = -1e30f;
        #pragma unroll
        for (int k = 0; k < KW; ++k) { v[k] = w[h * KW + k]; m = fmaxf(m, v[k]); }
        float s = 0.f;
        #pragma unroll
        for (int k = 0; k < KW; ++k) { v[k] = expf(v[k] - m); s += v[k]; }
        float inv = 1.f / s;
        #pragma unroll
        for (int k = 0; k < KW; ++k) wr[h * KW + (KW - 1 - k)] = v[k] * inv;
    }
}

// Double-buffered register window: old[31] (halo rows t0-31..t0-1) and
// cur[31] (rows t0..t0+30) are SEPARATE arrays, so all 62 loads issue up
// front with no WAR hazard against the FMA phase (round-2 version rotated
// one array and serialized loads behind consumers).
__global__ __launch_bounds__(TPB) void lconv_kernel(const float2* __restrict__ x,
                                                    const float* __restrict__ wr,
                                                    float2* __restrict__ out) {
    const int C2 = C_ / 2;
    const int c2 = blockIdx.x * TPB + threadIdx.x;   // float2 channel-pair index
    const int h  = c2 >> 5;                          // pair shares one head
    const int b  = blockIdx.z;
    const int t0 = blockIdx.y * KW;

    const float2* px = x   + (size_t)b * T_ * C2 + c2;
    float2*       po = out + (size_t)b * T_ * C2 + c2;

    float wv[KW];
    #pragma unroll
    for (int j = 0; j < KW; ++j) wv[j] = wr[h * KW + j];

    float2 old[KW], cur[KW];

    if (blockIdx.y == 0) {
        #pragma unroll
        for (int s = 0; s < KW; ++s) old[s] = make_float2(0.f, 0.f);
    } else {
        #pragma unroll
        for (int s = 0; s < KW; ++s) old[s] = px[(size_t)(t0 - KW + s) * C2];
    }

    if (t0 + KW <= T_) {
        // interior tile: all 31 loads independent, issued before any FMA
        #pragma unroll
        for (int s = 0; s < KW; ++s) cur[s] = px[(size_t)(t0 + s) * C2];

        #pragma unroll
        for (int i = 0; i < KW; ++i) {
            float ax = 0.f, ay = 0.f;
            #pragma unroll
            for (int j = 0; j < KW; ++j) {
                const int d = i - j;                       // static after unroll
                const float2 v = (d >= 0) ? cur[d] : old[KW + d];
                ax = fmaf(wv[j], v.x, ax);
                ay = fmaf(wv[j], v.y, ay);
            }
            po[(size_t)(t0 + i) * C2] = make_float2(ax, ay);
        }
    } else {
        // tail tile (t0=2046): guarded loads/stores
        #pragma unroll
        for (int s = 0; s < KW; ++s) {
            const int t = t0 + s;
            float2 v = make_float2(0.f, 0.f);
            if (t < T_) v = px[(size_t)t * C2];
            cur[s] = v;
        }
        #pragma unroll
        for (int i = 0; i < KW; ++i) {
            const int t = t0 + i;
            if (t < T_) {
                float ax = 0.f, ay = 0.f;
                #pragma unroll
                for (int j = 0; j < KW; ++j) {
                    const int d = i - j;
                    const float2 v = (d >= 0) ? cur[d] : old[KW + d];
                    ax = fmaf(wv[j], v.x, ax);
                    ay = fmaf(wv[j], v.y, ay);
                }
                po[(size_t)t * C2] = make_float2(ax, ay);
            }
        }
    }
}

extern "C" void kernel_launch(void* const* d_in, const int* in_sizes, int n_in,
                              void* d_out, int out_size, void* d_ws, size_t ws_size,
                              hipStream_t stream) {
    const float* x = (const float*)d_in[0];
    const float* w = (const float*)d_in[1];
    float* out = (float*)d_out;
    float* wr  = (float*)d_ws;   // H*KW = 496 floats

    hipLaunchKernelGGL(softmax_rev_kernel, dim3(1), dim3(64), 0, stream, w, wr);

    dim3 grid(C_ / (TPB * 2), (T_ + KW - 1) / KW, B_);   // (2, 67, 16)
    hipLaunchKernelGGL(lconv_kernel, grid, dim3(TPB), 0, stream,
                       (const float2*)x, wr, (float2*)out);
}

// Round 4
// 56.642 us; speedup vs baseline: 1.2661x; 1.2661x over previous
//
#include <hip/hip_runtime.h>
#include <math.h>

// (B,T,C)=(16,2048,1024), H=16, K=31, R=64, causal pad P=30.
// out[b,t,c] = sum_{j=0..30} w_rev[h(c),j] * x[b,t-j,c],  w_rev[j] = softmax(w)[30-j]
#define TPB 256
#define KW  31
#define TT  16            // outputs per thread
#define SUB 8             // t-subtiles per block (tid>>5)
#define BT  (TT * SUB)    // 128 t-rows per block
constexpr int B_ = 16, T_ = 2048, C_ = 1024, H_ = 16;
constexpr int C2 = C_ / 2;     // float2 pairs per row
constexpr int PPH = 32;        // float2 pairs per head (R=64 channels)

__global__ void softmax_rev_kernel(const float* __restrict__ w, float* __restrict__ wr) {
    int h = threadIdx.x;
    if (h < H_) {
        float v[KW];
        float m = -1e30f;
        #pragma unroll
        for (int k = 0; k < KW; ++k) { v[k] = w[h * KW + k]; m = fmaxf(m, v[k]); }
        float s = 0.f;
        #pragma unroll
        for (int k = 0; k < KW; ++k) { v[k] = expf(v[k] - m); s += v[k]; }
        float inv = 1.f / s;
        #pragma unroll
        for (int k = 0; k < KW; ++k) wr[h * KW + (KW - 1 - k)] = v[k] * inv;
    }
}

// Block = one head (weights block-uniform -> SGPRs via s_load).
// Thread = 1 float2 channel-pair x 16 t-rows. Window of 46 rows loaded in a
// single phase, pinned ahead of compute by sched_barrier(0) so all 46 loads
// stay in flight (23.5 KB/wave of MLP). Round-3's compiler re-serialization
// (VGPR stuck at 88) is what this kills.
__global__ __launch_bounds__(TPB, 2) void lconv_kernel(const float2* __restrict__ x,
                                                       const float* __restrict__ wr,
                                                       float2* __restrict__ out) {
    const int h    = blockIdx.x;            // head — block-uniform
    const int pair = threadIdx.x & 31;      // pair within head
    const int sub  = threadIdx.x >> 5;      // t-subtile (wave-uniform halves)
    const int b    = blockIdx.z;
    const int t0   = blockIdx.y * BT + sub * TT;
    const int c2   = h * PPH + pair;

    // weights: block-uniform address -> scalar loads, v_fmac takes 1 SGPR
    float wv[KW];
    #pragma unroll
    for (int j = 0; j < KW; ++j) wv[j] = wr[h * KW + j];

    const float2* px = x   + (size_t)b * T_ * C2 + c2;
    float2*       po = out + (size_t)b * T_ * C2 + c2;

    // win[s] = x[t0 - 30 + s],  s = 0..45
    float2 win[TT + KW - 1];
    if (blockIdx.y == 0 && sub < 2) {       // wave-uniform guard (only t<0 cases)
        #pragma unroll
        for (int s = 0; s < TT + KW - 1; ++s) {
            const int t = t0 - (KW - 1) + s;
            win[s] = (t >= 0) ? px[(size_t)t * C2] : make_float2(0.f, 0.f);
        }
    } else {
        #pragma unroll
        for (int s = 0; s < TT + KW - 1; ++s) {
            const int t = t0 - (KW - 1) + s;
            win[s] = px[(size_t)t * C2];
        }
    }

    __builtin_amdgcn_sched_barrier(0);      // pin: no load sinks below, no FMA hoists above

    #pragma unroll
    for (int i = 0; i < TT; ++i) {
        float ax = 0.f, ay = 0.f;
        #pragma unroll
        for (int j = 0; j < KW; ++j) {
            const float2 v = win[i + KW - 1 - j];   // static index
            ax = fmaf(wv[j], v.x, ax);
            ay = fmaf(wv[j], v.y, ay);
        }
        po[(size_t)(t0 + i) * C2] = make_float2(ax, ay);
    }
}

extern "C" void kernel_launch(void* const* d_in, const int* in_sizes, int n_in,
                              void* d_out, int out_size, void* d_ws, size_t ws_size,
                              hipStream_t stream) {
    const float* x = (const float*)d_in[0];
    const float* w = (const float*)d_in[1];
    float* out = (float*)d_out;
    float* wr  = (float*)d_ws;   // H*KW = 496 floats

    hipLaunchKernelGGL(softmax_rev_kernel, dim3(1), dim3(64), 0, stream, w, wr);

    dim3 grid(H_, T_ / BT, B_);   // (16, 16, 16) = 4096 blocks
    hipLaunchKernelGGL(lconv_kernel, grid, dim3(TPB), 0, stream,
                       (const float2*)x, wr, (float2*)out);
}

// Round 5
// 50.672 us; speedup vs baseline: 1.4152x; 1.1178x over previous
//
#include <hip/hip_runtime.h>
#include <math.h>

// (B,T,C)=(16,2048,1024), H=16, K=31, R=64, causal pad P=30.
// out[b,t,c] = sum_{j=0..30} w_rev[h(c),j] * x[b,t-j,c],  w_rev[j] = softmax(w)[30-j]
#define TPB  256
#define KW   31
#define HALO (KW - 1)          // 30
#define TT   16                // outputs per thread
#define SUB  8                 // t-subtiles per block
#define BT   (TT * SUB)        // 128 t-rows per block
#define ROWS (BT + HALO)       // 158 staged rows (compute uses s=0..157)
#define RQ   40                // staging quads (4 rows each -> 160 rows in LDS)
constexpr int B_ = 16, T_ = 2048, C_ = 1024, H_ = 16;
constexpr int C2 = C_ / 2;     // float2 pairs per t-row (512)
constexpr int PPH = 32;        // float2 pairs per head (R=64 channels)

__global__ void softmax_rev_kernel(const float* __restrict__ w, float* __restrict__ wr) {
    int h = threadIdx.x;
    if (h < H_) {
        float v[KW];
        float m = -1e30f;
        #pragma unroll
        for (int k = 0; k < KW; ++k) { v[k] = w[h * KW + k]; m = fmaxf(m, v[k]); }
        float s = 0.f;
        #pragma unroll
        for (int k = 0; k < KW; ++k) { v[k] = expf(v[k] - m); s += v[k]; }
        float inv = 1.f / s;
        #pragma unroll
        for (int k = 0; k < KW; ++k) wr[h * KW + (KW - 1 - k)] = v[k] * inv;
    }
}

// Block = (head h, 128-row t-tile, batch b). Stage 160 rows x 256 B into LDS
// with async global_load_lds (width 16, linear dest), one barrier, then
// accumulator-major compute: per LDS row read (ds_read_b64) update the
// subset of 16 float2 accumulators that touch it. No per-thread global halo,
// no load/compute phase starvation (other resident blocks stage while this
// one computes).
__global__ __launch_bounds__(TPB) void lconv_kernel(const float* __restrict__ x,
                                                    const float* __restrict__ wr,
                                                    float* __restrict__ out) {
    __shared__ float smem[4 * RQ * 64];      // 160 rows * 64 floats = 40 KB
    const int h   = blockIdx.x;
    const int b   = blockIdx.z;
    const int t0b = blockIdx.y * BT;
    const int tid  = threadIdx.x;
    const int lane = tid & 63;
    const int wid  = tid >> 6;

    // ---- stage: quad q = rows 4q..4q+3; lane l -> row 4q+(l>>4), 16B chunk (l&15)
    const int qrow  = lane >> 4;
    const int chunk = lane & 15;
    const float* xh = x + (size_t)b * T_ * C_ + h * 64;   // head base
    #pragma unroll
    for (int q = wid; q < RQ; q += 4) {
        int t = t0b - HALO + 4 * q + qrow;
        t = min(max(t, 0), T_ - 1);          // clamp: y==0 halo (zeroed below), y==15 overhang (unused)
        const float* gsrc = xh + (size_t)t * C_ + chunk * 4;
        __builtin_amdgcn_global_load_lds(
            (const __attribute__((address_space(1))) uint32_t*)gsrc,
            (__attribute__((address_space(3))) uint32_t*)(smem + q * 256),
            16, 0, 0);
    }
    __syncthreads();                          // drains vmcnt -> LDS stable
    if (blockIdx.y == 0) {                    // true zero-pad for t<0
        for (int k = tid; k < HALO * 64; k += TPB) smem[k] = 0.f;
        __syncthreads();
    }

    // ---- compute
    const int pair = tid & 31;                // float2 pair within head
    const int sub  = tid >> 5;                // t-subtile 0..7

    float wv[KW];                             // block-uniform -> scalar loads
    #pragma unroll
    for (int j = 0; j < KW; ++j) wv[j] = wr[h * KW + j];

    float2 acc[TT];
    #pragma unroll
    for (int i = 0; i < TT; ++i) acc[i] = make_float2(0.f, 0.f);

    const float2* sm2 = (const float2*)smem;
    #pragma unroll
    for (int sr = 0; sr < TT + HALO; ++sr) {  // 46 rows per thread
        const float2 v = sm2[(size_t)(sub * TT + sr) * PPH + pair];
        const int ilo = (sr - HALO < 0) ? 0 : sr - HALO;
        const int ihi = (sr < TT - 1) ? sr : TT - 1;
        #pragma unroll
        for (int i = ilo; i <= ihi; ++i) {    // j = i + HALO - sr, static
            const float wj = wv[i + HALO - sr];
            acc[i].x = fmaf(wj, v.x, acc[i].x);
            acc[i].y = fmaf(wj, v.y, acc[i].y);
        }
    }

    float2* po = (float2*)out + ((size_t)b * T_ + t0b + sub * TT) * C2 + h * PPH + pair;
    #pragma unroll
    for (int i = 0; i < TT; ++i) po[(size_t)i * C2] = acc[i];
}

extern "C" void kernel_launch(void* const* d_in, const int* in_sizes, int n_in,
                              void* d_out, int out_size, void* d_ws, size_t ws_size,
                              hipStream_t stream) {
    const float* x = (const float*)d_in[0];
    const float* w = (const float*)d_in[1];
    float* out = (float*)d_out;
    float* wr  = (float*)d_ws;   // H*KW = 496 floats

    hipLaunchKernelGGL(softmax_rev_kernel, dim3(1), dim3(64), 0, stream, w, wr);

    dim3 grid(H_, T_ / BT, B_);   // (16, 16, 16) = 4096 blocks
    hipLaunchKernelGGL(lconv_kernel, grid, dim3(TPB), 0, stream, x, wr, out);
}